// Round 3
// baseline (525.345 us; speedup 1.0000x reference)
//
#include <hip/hip_runtime.h>
#include <math.h>

#define DD 192
#define HH 192
#define WW 384
#define WV 575           // W + D - 1
#define NCHUNK 8
#define DPC 24           // d-planes per chunk
#define TPB 384          // one thread per pixel
#define ROUNDS 12        // 2 planes per round

// Kernel A: per-(h, d-chunk) partial online-softmax states.
// Each d-plane row is read from HBM once (trimmed: plane d only needs
// elements [0, 574-d]), staged in LDS, and serves BOTH the aligned and the
// diagonal pass. Software pipeline: two register sets (A/B) each prefetch a
// 2-plane round a full round ahead of its LDS store, so HBM latency hides
// behind compute + barriers. ws layout: [h][chunk][12 fields][WW] floats.
__global__ __launch_bounds__(TPB, 4) void vr_partial(const float* __restrict__ v,
                                                     float* __restrict__ ws) {
    const int t = threadIdx.x;             // pixel w, 0..383
    const int h = blockIdx.x >> 3;
    const int chunk = blockIdx.x & 7;
    const int d0 = chunk * DPC;

    const size_t dstride = (size_t)HH * WV;       // 110400
    const size_t cstride = (size_t)DD * dstride;  // 21196800
    const float* base = v + (size_t)h * WV + (size_t)d0 * dstride + t;

    __shared__ float rows[2][4][WV];              // 18.4 KB, single-buffered

    float m1 = -INFINITY, l1 = 0.f, a1 = 0.f, c10 = 0.f, c11 = 0.f, c12 = 0.f;
    float m2 = -INFINITY, l2 = 0.f, a2 = 0.f, c20 = 0.f, c21 = 0.f, c22 = 0.f;

    float A0[4], A0t[4], A1[4], A1t[4];
    float B0[4], B0t[4], B1[4], B1t[4];

    // plane pp (0..23): load elements t and, if needed, t+384 (trimmed by d)
#define LOADP(M, Mt, pp) do {                                            \
        const float* r_ = base + (size_t)(pp) * dstride;                 \
        const int tl_ = (DD - 1) - (d0 + (pp));                          \
        _Pragma("unroll")                                                \
        for (int c_ = 0; c_ < 4; ++c_) {                                 \
            M[c_] = r_[c_ * cstride];                                    \
            if (t < tl_) Mt[c_] = r_[c_ * cstride + TPB];                \
        } } while (0)

#define STOREP(M, Mt, i, pp) do {                                        \
        const int tl_ = (DD - 1) - (d0 + (pp));                          \
        _Pragma("unroll")                                                \
        for (int c_ = 0; c_ < 4; ++c_) {                                 \
            rows[i][c_][t] = M[c_];                                      \
            if (t < tl_) rows[i][c_][t + TPB] = Mt[c_];                  \
        } } while (0)

#define COMPUTEP(i, pp) do {                                             \
        const int sh_ = (DD - 1) - (d0 + (pp));                          \
        const float dv_ = (float)sh_;                                    \
        const float b1_  = rows[i][0][t];                                \
        const float x10_ = rows[i][1][t];                                \
        const float x11_ = rows[i][2][t];                                \
        const float x12_ = rows[i][3][t];                                \
        const float b2_  = rows[i][0][t + sh_];                          \
        const float x20_ = rows[i][1][t + sh_];                          \
        const float x21_ = rows[i][2][t + sh_];                          \
        const float x22_ = rows[i][3][t + sh_];                          \
        float nm_ = fmaxf(m1, b1_);                                      \
        float s_  = __expf(m1 - nm_);                                    \
        float pr_ = __expf(b1_ - nm_);                                   \
        l1  = l1  * s_ + pr_;                                            \
        a1  = a1  * s_ + pr_ * dv_;                                      \
        c10 = c10 * s_ + pr_ * x10_;                                     \
        c11 = c11 * s_ + pr_ * x11_;                                     \
        c12 = c12 * s_ + pr_ * x12_;                                     \
        m1 = nm_;                                                        \
        nm_ = fmaxf(m2, b2_);                                            \
        s_  = __expf(m2 - nm_);                                          \
        pr_ = __expf(b2_ - nm_);                                         \
        l2  = l2  * s_ + pr_;                                            \
        a2  = a2  * s_ + pr_ * dv_;                                      \
        c20 = c20 * s_ + pr_ * x20_;                                     \
        c21 = c21 * s_ + pr_ * x21_;                                     \
        c22 = c22 * s_ + pr_ * x22_;                                     \
        m2 = nm_;                                                        \
    } while (0)

    // prime the pipeline: A = round 0 (planes 0,1)
    LOADP(A0, A0t, 0);
    LOADP(A1, A1t, 1);

    for (int r = 0; r < ROUNDS; r += 2) {
        const int pA = r * 2;            // A-round planes pA, pA+1
        const int pB = pA + 2;           // B-round planes pB, pB+1
        LOADP(B0, B0t, pB);
        LOADP(B1, B1t, pB + 1);
        __syncthreads();                 // prev round's LDS readers done
        STOREP(A0, A0t, 0, pA);
        STOREP(A1, A1t, 1, pA + 1);
        __syncthreads();
        if (r + 2 < ROUNDS) {            // A prefetch for next iteration
            LOADP(A0, A0t, pA + 4);
            LOADP(A1, A1t, pA + 5);
        }
        COMPUTEP(0, pA);
        COMPUTEP(1, pA + 1);
        __syncthreads();
        STOREP(B0, B0t, 0, pB);
        STOREP(B1, B1t, 1, pB + 1);
        __syncthreads();
        COMPUTEP(0, pB);
        COMPUTEP(1, pB + 1);
    }

    float* wp = ws + (((size_t)h * NCHUNK + chunk) * 12) * WW + t;
    wp[0 * WW] = m1;  wp[1 * WW] = l1;   wp[2 * WW]  = a1;
    wp[3 * WW] = c10; wp[4 * WW] = c11;  wp[5 * WW]  = c12;
    wp[6 * WW] = m2;  wp[7 * WW] = l2;   wp[8 * WW]  = a2;
    wp[9 * WW] = c20; wp[10 * WW] = c21; wp[11 * WW] = c22;
}

// Kernel B: merge the 8 chunk-states per pixel, write final outputs.
__global__ __launch_bounds__(256, 4) void vr_merge(const float* __restrict__ ws,
                                                   float* __restrict__ out) {
    const int pix = blockIdx.x * 256 + threadIdx.x;   // 0 .. 73727
    const int h = pix / WW;
    const int w = pix - h * WW;
    const int HW = HH * WW;

    #pragma unroll
    for (int pass = 0; pass < 2; ++pass) {
        float M = -INFINITY, L = 0.f, A = 0.f, C0 = 0.f, C1 = 0.f, C2 = 0.f;
        #pragma unroll
        for (int ch = 0; ch < NCHUNK; ++ch) {
            const float* q = ws + (((size_t)h * NCHUNK + ch) * 12 + pass * 6) * WW + w;
            const float mm = q[0];
            const float nm = fmaxf(M, mm);
            const float s0 = __expf(M - nm);
            const float s1 = __expf(mm - nm);
            L  = L  * s0 + q[1 * WW] * s1;
            A  = A  * s0 + q[2 * WW] * s1;
            C0 = C0 * s0 + q[3 * WW] * s1;
            C1 = C1 * s0 + q[4 * WW] * s1;
            C2 = C2 * s0 + q[5 * WW] * s1;
            M = nm;
        }
        const float inv = 1.0f / L;
        const int o = h * WW + w;
        out[(pass * 3 + 0) * HW + o] = C0 * inv;
        out[(pass * 3 + 1) * HW + o] = C1 * inv;
        out[(pass * 3 + 2) * HW + o] = C2 * inv;
        out[(6 + pass) * HW + o]     = A * inv;
    }
}

extern "C" void kernel_launch(void* const* d_in, const int* in_sizes, int n_in,
                              void* d_out, int out_size, void* d_ws, size_t ws_size,
                              hipStream_t stream) {
    const float* v = (const float*)d_in[0];
    float* out = (float*)d_out;
    float* ws = (float*)d_ws;    // needs 192*8*12*384*4 B = 28.3 MB
    vr_partial<<<HH * NCHUNK, TPB, 0, stream>>>(v, ws);
    vr_merge<<<(HH * WW) / 256, 256, 0, stream>>>(ws, out);
}

// Round 4
// 461.490 us; speedup vs baseline: 1.1384x; 1.1384x over previous
//
#include <hip/hip_runtime.h>
#include <math.h>

#define DD 192
#define HH 192
#define WW 384
#define WV 575           // W + D - 1
#define NCHUNK 8
#define DPC 24           // d-planes per chunk
#define TPB 384          // one thread per pixel
#define BATCH 3          // planes per barrier window
#define NB (DPC / BATCH) // 8 batches

// Kernel A: per-(h, d-chunk) partial online-softmax states.
// Each d-plane row is read from HBM once (trimmed: plane d needs elements
// [0, 574-d] only), staged in LDS, and serves both the aligned and the
// diagonal pass. Pipeline: 3-plane batches, ping-pong LDS buffers, ONE
// __syncthreads per batch. The vmcnt(0) drain the compiler emits at each
// barrier then covers a ~42 KB/CU in-flight window (BW-bound, not
// latency-bound), and next-batch delivery overlaps compute + LDS stores.
__global__ __launch_bounds__(TPB, 4) void vr_partial(const float* __restrict__ v,
                                                     float* __restrict__ ws) {
    const int t = threadIdx.x;             // pixel w, 0..383
    const int h = blockIdx.x >> 3;
    const int chunk = blockIdx.x & 7;
    const int d0 = chunk * DPC;

    const size_t dstride = (size_t)HH * WV;       // 110400
    const size_t cstride = (size_t)DD * dstride;  // 21196800
    const float* base = v + (size_t)h * WV + (size_t)d0 * dstride + t;

    __shared__ float rows[2][BATCH][4][WV];       // 55.3 KB ping-pong

    float m1 = -INFINITY, l1 = 0.f, a1 = 0.f, c10 = 0.f, c11 = 0.f, c12 = 0.f;
    float m2 = -INFINITY, l2 = 0.f, a2 = 0.f, c20 = 0.f, c21 = 0.f, c22 = 0.f;

    float R[2][BATCH][4];    // main element (t) per set/plane/channel
    float Rt[2][BATCH][4];   // tail element (t+384), valid when t < 191-d

    // Load batch starting at plane pb into register set s (8-9 loads/plane).
#define LOADB(s, pb) do {                                                 \
        _Pragma("unroll")                                                 \
        for (int pl_ = 0; pl_ < BATCH; ++pl_) {                           \
            const float* r_ = base + (size_t)((pb) + pl_) * dstride;      \
            const int tl_ = (DD - 1) - (d0 + (pb) + pl_);                 \
            _Pragma("unroll")                                             \
            for (int c_ = 0; c_ < 4; ++c_) {                              \
                R[s][pl_][c_] = r_[c_ * cstride];                         \
                if (t < tl_) Rt[s][pl_][c_] = r_[c_ * cstride + TPB];     \
            }                                                             \
        } } while (0)

    // Store register set s into LDS buffer buf.
#define STOREB(s, buf, pb) do {                                           \
        _Pragma("unroll")                                                 \
        for (int pl_ = 0; pl_ < BATCH; ++pl_) {                           \
            const int tl_ = (DD - 1) - (d0 + (pb) + pl_);                 \
            _Pragma("unroll")                                             \
            for (int c_ = 0; c_ < 4; ++c_) {                              \
                rows[buf][pl_][c_][t] = R[s][pl_][c_];                    \
                if (t < tl_) rows[buf][pl_][c_][t + TPB] = Rt[s][pl_][c_];\
            }                                                             \
        } } while (0)

    // Online-softmax update for the BATCH planes in LDS buffer buf.
#define COMPUTEB(buf, pb) do {                                            \
        _Pragma("unroll")                                                 \
        for (int pl_ = 0; pl_ < BATCH; ++pl_) {                           \
            const int sh_ = (DD - 1) - (d0 + (pb) + pl_);                 \
            const float dv_ = (float)sh_;                                 \
            const float b1_  = rows[buf][pl_][0][t];                      \
            const float x10_ = rows[buf][pl_][1][t];                      \
            const float x11_ = rows[buf][pl_][2][t];                      \
            const float x12_ = rows[buf][pl_][3][t];                      \
            const float b2_  = rows[buf][pl_][0][t + sh_];                \
            const float x20_ = rows[buf][pl_][1][t + sh_];                \
            const float x21_ = rows[buf][pl_][2][t + sh_];                \
            const float x22_ = rows[buf][pl_][3][t + sh_];                \
            float nm_ = fmaxf(m1, b1_);                                   \
            float s_  = __expf(m1 - nm_);                                 \
            float pr_ = __expf(b1_ - nm_);                                \
            l1  = l1  * s_ + pr_;                                         \
            a1  = a1  * s_ + pr_ * dv_;                                   \
            c10 = c10 * s_ + pr_ * x10_;                                  \
            c11 = c11 * s_ + pr_ * x11_;                                  \
            c12 = c12 * s_ + pr_ * x12_;                                  \
            m1 = nm_;                                                     \
            nm_ = fmaxf(m2, b2_);                                         \
            s_  = __expf(m2 - nm_);                                       \
            pr_ = __expf(b2_ - nm_);                                      \
            l2  = l2  * s_ + pr_;                                         \
            a2  = a2  * s_ + pr_ * dv_;                                   \
            c20 = c20 * s_ + pr_ * x20_;                                  \
            c21 = c21 * s_ + pr_ * x21_;                                  \
            c22 = c22 * s_ + pr_ * x22_;                                  \
            m2 = nm_;                                                     \
        } } while (0)

    // prologue: batch 0 -> buf 0
    LOADB(0, 0);
    STOREB(0, 0, 0);         // compiler inserts the vmcnt wait for R[0]
    __syncthreads();

    #pragma unroll
    for (int b = 0; b < NB; ++b) {
        const int cur = b & 1;
        const int nxt = (b + 1) & 1;
        if (b + 1 < NB) LOADB(nxt, (b + 1) * BATCH);   // async issue
        COMPUTEB(cur, b * BATCH);                      // overlaps delivery
        if (b + 1 < NB) STOREB(nxt, nxt, (b + 1) * BATCH);
        __syncthreads();     // one drain per batch (BW wait, not latency)
    }

    float* wp = ws + (((size_t)h * NCHUNK + chunk) * 12) * WW + t;
    wp[0 * WW] = m1;  wp[1 * WW] = l1;   wp[2 * WW]  = a1;
    wp[3 * WW] = c10; wp[4 * WW] = c11;  wp[5 * WW]  = c12;
    wp[6 * WW] = m2;  wp[7 * WW] = l2;   wp[8 * WW]  = a2;
    wp[9 * WW] = c20; wp[10 * WW] = c21; wp[11 * WW] = c22;
}

// Kernel B: merge the 8 chunk-states per pixel, write final outputs.
__global__ __launch_bounds__(256, 4) void vr_merge(const float* __restrict__ ws,
                                                   float* __restrict__ out) {
    const int pix = blockIdx.x * 256 + threadIdx.x;   // 0 .. 73727
    const int h = pix / WW;
    const int w = pix - h * WW;
    const int HW = HH * WW;

    #pragma unroll
    for (int pass = 0; pass < 2; ++pass) {
        float M = -INFINITY, L = 0.f, A = 0.f, C0 = 0.f, C1 = 0.f, C2 = 0.f;
        #pragma unroll
        for (int ch = 0; ch < NCHUNK; ++ch) {
            const float* q = ws + (((size_t)h * NCHUNK + ch) * 12 + pass * 6) * WW + w;
            const float mm = q[0];
            const float nm = fmaxf(M, mm);
            const float s0 = __expf(M - nm);
            const float s1 = __expf(mm - nm);
            L  = L  * s0 + q[1 * WW] * s1;
            A  = A  * s0 + q[2 * WW] * s1;
            C0 = C0 * s0 + q[3 * WW] * s1;
            C1 = C1 * s0 + q[4 * WW] * s1;
            C2 = C2 * s0 + q[5 * WW] * s1;
            M = nm;
        }
        const float inv = 1.0f / L;
        const int o = h * WW + w;
        out[(pass * 3 + 0) * HW + o] = C0 * inv;
        out[(pass * 3 + 1) * HW + o] = C1 * inv;
        out[(pass * 3 + 2) * HW + o] = C2 * inv;
        out[(6 + pass) * HW + o]     = A * inv;
    }
}

extern "C" void kernel_launch(void* const* d_in, const int* in_sizes, int n_in,
                              void* d_out, int out_size, void* d_ws, size_t ws_size,
                              hipStream_t stream) {
    const float* v = (const float*)d_in[0];
    float* out = (float*)d_out;
    float* ws = (float*)d_ws;    // needs 192*8*12*384*4 B = 28.3 MB
    vr_partial<<<HH * NCHUNK, TPB, 0, stream>>>(v, ws);
    vr_merge<<<(HH * WW) / 256, 256, 0, stream>>>(ws, out);
}